// Round 7
// baseline (239.987 us; speedup 1.0000x reference)
//
#include <hip/hip_runtime.h>
#include <math.h>

constexpr int NCL = 64;
constexpr int NN  = 8;
constexpr int NG  = 2;      // batch elems per block
constexpr int NT  = 512;    // 8 waves

typedef __attribute__((ext_vector_type(4))) float f32x4;
typedef __attribute__((ext_vector_type(2))) float f32x2;
typedef __attribute__((ext_vector_type(8))) short s16x8;
#define MFMA __builtin_amdgcn_mfma_f32_16x16x32_bf16

// workspace layout offsets (units of s16x8 = 16 B)
constexpr int OFF_ENC = 0;      // 8 frags  (hi 512 | lo 512)
constexpr int OFF_S0  = 1024;
constexpr int OFF_S1  = 2048;
constexpr int OFF_R0  = 3072;   // 32 frags (hi 2048 | lo 2048)
constexpr int OFF_A0  = 7168;
constexpr int OFF_A1  = 11264;  // 16 frags (hi 1024 | lo 1024)
constexpr int OFF_R1  = 13312;
constexpr int OFF_R2  = 15360;  // 8 frags  (hi 512 | lo 512)

__device__ __forceinline__ float elu_f(float x) { return x > 0.f ? x : __expf(x) - 1.f; }

__device__ __forceinline__ unsigned f2u(float x) { union { float f; unsigned u; } c; c.f = x; return c.u; }
__device__ __forceinline__ float u2f(unsigned u) { union { unsigned u; float f; } c; c.u = u; return c.f; }

// Pack 8 fp32 -> bf16 hi (truncated) + bf16 lo (truncated residual) fragments.
__device__ __forceinline__ void splitpack8(const float v[8], s16x8& hi, s16x8& lo) {
    union { s16x8 s; unsigned u[4]; } H, L;
    #pragma unroll
    for (int e = 0; e < 8; e += 2) {
        H.u[e >> 1] = __builtin_amdgcn_perm(f2u(v[e + 1]), f2u(v[e]), 0x07060302u);
        f32x2 t = {u2f(f2u(v[e]) & 0xffff0000u), u2f(f2u(v[e + 1]) & 0xffff0000u)};
        f32x2 r = (f32x2){v[e], v[e + 1]} - t;          // v_pk_add_f32
        L.u[e >> 1] = __builtin_amdgcn_perm(f2u(r.y), f2u(r.x), 0x07060302u);
    }
    hi = H.s; lo = L.s;
}

// A-fragment (split hi/lo) from fp32 LDS activations, row stride 68.
__device__ __forceinline__ void afrag_split(const float* act, int row, int kbase,
                                            s16x8& hi, s16x8& lo) {
    const float4 v0 = *(const float4*)(act + row * 68 + kbase);
    const float4 v1 = *(const float4*)(act + row * 68 + kbase + 4);
    const float v[8] = {v0.x, v0.y, v0.z, v0.w, v1.x, v1.y, v1.z, v1.w};
    splitpack8(v, hi, lo);
}

// 16x16 tile of act[16x64] @ W[64x64] from packed fragments (8-frag matrix).
__device__ __forceinline__ f32x4 node_tile_pk(const float* act, const s16x8* __restrict__ wb,
                                              int mt, int nt, int lane) {
    const int row = mt * 16 + (lane & 15);
    const int g   = lane >> 4;
    f32x4 acc = {0.f, 0.f, 0.f, 0.f};
    #pragma unroll
    for (int kg = 0; kg < 2; ++kg) {
        s16x8 ah, al;
        afrag_split(act, row, kg * 32 + g * 8, ah, al);
        const s16x8 bh = wb[(kg * 4 + nt) * 64 + lane];
        const s16x8 bl = wb[512 + (kg * 4 + nt) * 64 + lane];
        acc = MFMA(ah, bh, acc, 0, 0, 0);
        acc = MFMA(ah, bl, acc, 0, 0, 0);
        acc = MFMA(al, bh, acc, 0, 0, 0);
    }
    return acc;
}

// X1 pair-feature fragment with packed-fp32 math:
// elu(A[f] + B[f] + d*wd[f]) for f = fbase..fbase+7
__device__ __forceinline__ void x1frag(const float* Arow, const float* Brow,
                                       const float* wdg, float d, int fbase,
                                       s16x8& hi, s16x8& lo) {
    const float4 a0 = *(const float4*)(Arow + fbase);
    const float4 a1 = *(const float4*)(Arow + fbase + 4);
    const float4 c0 = *(const float4*)(Brow + fbase);
    const float4 c1 = *(const float4*)(Brow + fbase + 4);
    const float4 w0 = *(const float4*)(wdg + fbase);
    const float4 w1 = *(const float4*)(wdg + fbase + 4);
    const f32x2 A2[4] = {{a0.x, a0.y}, {a0.z, a0.w}, {a1.x, a1.y}, {a1.z, a1.w}};
    const f32x2 C2[4] = {{c0.x, c0.y}, {c0.z, c0.w}, {c1.x, c1.y}, {c1.z, c1.w}};
    const f32x2 W2[4] = {{w0.x, w0.y}, {w0.z, w0.w}, {w1.x, w1.y}, {w1.z, w1.w}};
    const f32x2 dd = {d, d};
    union { s16x8 s; unsigned u[4]; } H, L;
    #pragma unroll
    for (int p = 0; p < 4; ++p) {
        const f32x2 t = __builtin_elementwise_fma(dd, W2[p], A2[p] + C2[p]); // pk_add + pk_fma
        const float v0 = elu_f(t.x), v1 = elu_f(t.y);
        H.u[p] = __builtin_amdgcn_perm(f2u(v1), f2u(v0), 0x07060302u);
        const f32x2 tr = {u2f(f2u(v0) & 0xffff0000u), u2f(f2u(v1) & 0xffff0000u)};
        const f32x2 r  = (f32x2){v0, v1} - tr;                               // pk_add
        L.u[p] = __builtin_amdgcn_perm(f2u(r.y), f2u(r.x), 0x07060302u);
    }
    hi = H.s; lo = L.s;
}

// ---------------- prep: pack weights into split-bf16 fragment planes ----------------
__device__ __forceinline__ short bfh_rn(float x) {
    union { float f; unsigned u; } c; c.f = x;
    return (short)((c.u + 0x7fffu + ((c.u >> 16) & 1u)) >> 16);
}
__device__ __forceinline__ void split_tr(float x, short& hi, short& lo) {
    union { float f; unsigned u; } c; c.f = x;
    hi = (short)(c.u >> 16);
    union { unsigned u; float f; } t; t.u = c.u & 0xffff0000u;
    lo = bfh_rn(x - t.f);
}

__global__ __launch_bounds__(64)
void prep_kernel(const float* __restrict__ We,  const float* __restrict__ Ws0,
                 const float* __restrict__ Ws1, const float* __restrict__ Wr0,
                 const float* __restrict__ Wa0, const float* __restrict__ Wa1,
                 const float* __restrict__ Wr1, const float* __restrict__ Wr2,
                 s16x8* __restrict__ ws)
{
    const int b = blockIdx.x, lane = threadIdx.x;
    const float* W; int nnt, nfrag, base, frag;
    if      (b < 8)   { W = We;  nnt = 4; nfrag = 8;  base = OFF_ENC; frag = b; }
    else if (b < 16)  { W = Ws0; nnt = 4; nfrag = 8;  base = OFF_S0;  frag = b - 8; }
    else if (b < 24)  { W = Ws1; nnt = 4; nfrag = 8;  base = OFF_S1;  frag = b - 16; }
    else if (b < 56)  { W = Wr0; nnt = 8; nfrag = 32; base = OFF_R0;  frag = b - 24; }
    else if (b < 88)  { W = Wa0; nnt = 8; nfrag = 32; base = OFF_A0;  frag = b - 56; }
    else if (b < 104) { W = Wa1; nnt = 4; nfrag = 16; base = OFF_A1;  frag = b - 88; }
    else if (b < 120) { W = Wr1; nnt = 4; nfrag = 16; base = OFF_R1;  frag = b - 104; }
    else              { W = Wr2; nnt = 4; nfrag = 8;  base = OFF_R2;  frag = b - 120; }
    const int kg = frag / nnt, nt = frag % nnt;
    const int N  = nnt * 16;
    const int g  = lane >> 4, col = nt * 16 + (lane & 15);
    s16x8 hi, lo;
    #pragma unroll
    for (int e = 0; e < 8; ++e) {
        short a, c; split_tr(W[(kg * 32 + g * 8 + e) * N + col], a, c);
        hi[e] = a; lo[e] = c;
    }
    ws[base + frag * 64 + lane]              = hi;
    ws[base + nfrag * 64 + frag * 64 + lane] = lo;
}

// ---------------- main ----------------
__global__ __launch_bounds__(NT, 8)
void gh_kernel(const float* __restrict__ S,
               const float* __restrict__ b_enc,
               const float* __restrict__ b_self0, const float* __restrict__ b_self1,
               const float* __restrict__ W_rel0,  const float* __restrict__ b_rel0,
               const float* __restrict__ b_rel1,  const float* __restrict__ b_rel2,
               const float* __restrict__ W_att0,  const float* __restrict__ b_att0,
               const float* __restrict__ b_att1,
               const float* __restrict__ W_att2,  const float* __restrict__ b_att2,
               const s16x8* __restrict__ wp,
               float* __restrict__ Out)
{
    // LDS: 3*4352 + 2*8448 + 512 + 64 + 1024 = 31,552 B  -> 4 blocks/CU (wave cap)
    __shared__ __align__(16) float sbuf[16 * 68];    // s; later self_dyn
    __shared__ __align__(16) float encb[16 * 68];    // enc; later Ubuf/Rbuf
    __shared__ __align__(16) float hbuf[16 * 68];    // h; later Tbuf
    __shared__ __align__(16) float ABm[2][16 * 132]; // reused: att A/B, then rel A/B
    __shared__ float d2l[2 * 64];
    __shared__ float cntl[16];
    __shared__ float wdl[2][128];                    // dist rows: 0 rel, 1 att

    const int tid  = threadIdx.x;
    const int w    = tid >> 6;
    const int lane = tid & 63;
    const int g    = lane >> 4;
    const int b0   = blockIdx.x * NG;
    float* sd   = sbuf;
    float* Tb   = hbuf;
    float* Ubuf = encb;        // [2][68]
    float* Rbuf = encb + 512;  // [2][64]

    // ---- P0: load s, dist rows ----
    {
        const float* src = S + (size_t)b0 * NN * NCL;
        for (int idx = tid; idx < 16 * 64; idx += NT)
            sbuf[(idx >> 6) * 68 + (idx & 63)] = src[idx];
        if (tid < 128) {
            wdl[0][tid] = W_rel0[128 * 128 + tid];
            wdl[1][tid] = W_att0[128 * 128 + tid];
        }
    }
    __syncthreads();

    if (tid < 128) {
        const int bi = tid >> 6, i = (tid >> 3) & 7, j = tid & 7;
        const float dx = sbuf[(bi * 8 + i) * 68 + 0] - sbuf[(bi * 8 + j) * 68 + 0];
        const float dy = sbuf[(bi * 8 + i) * 68 + 1] - sbuf[(bi * 8 + j) * 68 + 1];
        d2l[bi * 64 + i * 8 + j] = dx * dx + dy * dy;
    }

    // ---- P1: enc (waves 0-3) ----
    if (w < 4) {
        const int nt = w;
        f32x4 acc = node_tile_pk(sbuf, wp + OFF_ENC, 0, nt, lane);
        const int   col = nt * 16 + (lane & 15);
        const float be  = b_enc[col];
        #pragma unroll
        for (int reg = 0; reg < 4; ++reg) {
            const int row = g * 4 + reg;
            float v = acc[reg] + be;
            if (col < 2) v = sbuf[row * 68 + col];
            encb[row * 68 + col] = v;
        }
    }
    __syncthreads();

    // ---- P2: h = elu(enc @ W_self0 + b) (waves 0-3) ----
    if (w < 4) {
        const int nt = w;
        f32x4 acc = node_tile_pk(encb, wp + OFF_S0, 0, nt, lane);
        const int   col = nt * 16 + (lane & 15);
        const float bs  = b_self0[col];
        #pragma unroll
        for (int reg = 0; reg < 4; ++reg)
            hbuf[(g * 4 + reg) * 68 + col] = elu_f(acc[reg] + bs);
    }
    __syncthreads();

    // ---- P3a: self1 (waves 0-3) + att pair projections (all 8 waves) ----
    if (w < 4) {
        const int nt = w;
        f32x4 acc = node_tile_pk(hbuf, wp + OFF_S1, 0, nt, lane);
        const int   col = nt * 16 + (lane & 15);
        const float bs  = b_self1[col];
        #pragma unroll
        for (int reg = 0; reg < 4; ++reg) {
            const int row = g * 4 + reg;
            sd[row * 68 + col] = acc[reg] + bs + hbuf[row * 68 + col];
        }
    }
    {
        const int ntp = w;
        const int row = lane & 15;
        const int col = ntp * 16 + (lane & 15);
        s16x8 eh[2], el[2];
        afrag_split(encb, row, g * 8, eh[0], el[0]);
        afrag_split(encb, row, 32 + g * 8, eh[1], el[1]);
        #pragma unroll
        for (int m = 0; m < 2; ++m) {               // 0: A_att, 1: B_att
            const int kgo = m * 2;
            f32x4 acc = {0.f, 0.f, 0.f, 0.f};
            #pragma unroll
            for (int kg = 0; kg < 2; ++kg) {
                const s16x8 bh = wp[OFF_A0 + ((kgo + kg) * 8 + ntp) * 64 + lane];
                const s16x8 bl = wp[OFF_A0 + 2048 + ((kgo + kg) * 8 + ntp) * 64 + lane];
                acc = MFMA(eh[kg], bh, acc, 0, 0, 0);
                acc = MFMA(eh[kg], bl, acc, 0, 0, 0);
                acc = MFMA(el[kg], bh, acc, 0, 0, 0);
            }
            const float badd = (m == 0) ? b_att0[col] : 0.f;
            #pragma unroll
            for (int reg = 0; reg < 4; ++reg)
                ABm[m][(g * 4 + reg) * 132 + col] = acc[reg] + badd;
        }
    }
    __syncthreads();

    // ---- P4a: attention pass ----
    const int bi    = w >> 2;
    const int ihalf = (w >> 1) & 1;
    const int mt    = w & 1;
    const int pp    = (lane & 15) + 16 * mt;
    const int il    = pp >> 3, jj8 = pp & 7;
    const float* Arow = &ABm[0][(bi * 8 + ihalf * 4 + il) * 132];
    const float* Brow = &ABm[1][(bi * 8 + jj8) * 132];
    const float dpair = d2l[bi * 64 + (ihalf * 4 + il) * 8 + jj8];

    float attreg[4];
    {
        const float ba2 = b_att2[0];
        float wa2v[4];
        f32x4 acc[4];
        #pragma unroll
        for (int nt = 0; nt < 4; ++nt) {
            wa2v[nt] = W_att2[nt * 16 + (lane & 15)];
            const float b1 = b_att1[nt * 16 + (lane & 15)];
            acc[nt] = {b1, b1, b1, b1};
        }
        #pragma unroll
        for (int kg = 0; kg < 4; ++kg) {
            s16x8 ah, al;
            x1frag(Arow, Brow, &wdl[1][0], dpair, kg * 32 + g * 8, ah, al);
            #pragma unroll
            for (int nt = 0; nt < 4; ++nt) {
                const s16x8 bh = wp[OFF_A1 + (kg * 4 + nt) * 64 + lane];
                const s16x8 bl = wp[OFF_A1 + 1024 + (kg * 4 + nt) * 64 + lane];
                acc[nt] = MFMA(ah, bh, acc[nt], 0, 0, 0);
                acc[nt] = MFMA(ah, bl, acc[nt], 0, 0, 0);
                acc[nt] = MFMA(al, bh, acc[nt], 0, 0, 0);
            }
        }
        #pragma unroll
        for (int reg = 0; reg < 4; ++reg) {
            float s = 0.f;
            #pragma unroll
            for (int nt = 0; nt < 4; ++nt) s += elu_f(acc[nt][reg]) * wa2v[nt];
            s += __shfl_xor(s, 1, 64);
            s += __shfl_xor(s, 2, 64);
            s += __shfl_xor(s, 4, 64);
            s += __shfl_xor(s, 8, 64);
            attreg[reg] = 1.f / (1.f + __expf(-(s + ba2)));
        }
    }
    __syncthreads();   // everyone done reading att ABm

    // ---- P3b: rel pair projections into the same buffer ----
    {
        const int ntp = w;
        const int row = lane & 15;
        const int col = ntp * 16 + (lane & 15);
        s16x8 eh[2], el[2];
        afrag_split(encb, row, g * 8, eh[0], el[0]);
        afrag_split(encb, row, 32 + g * 8, eh[1], el[1]);
        #pragma unroll
        for (int m = 0; m < 2; ++m) {               // 0: A_rel, 1: B_rel
            const int kgo = m * 2;
            f32x4 acc = {0.f, 0.f, 0.f, 0.f};
            #pragma unroll
            for (int kg = 0; kg < 2; ++kg) {
                const s16x8 bh = wp[OFF_R0 + ((kgo + kg) * 8 + ntp) * 64 + lane];
                const s16x8 bl = wp[OFF_R0 + 2048 + ((kgo + kg) * 8 + ntp) * 64 + lane];
                acc = MFMA(eh[kg], bh, acc, 0, 0, 0);
                acc = MFMA(eh[kg], bl, acc, 0, 0, 0);
                acc = MFMA(el[kg], bh, acc, 0, 0, 0);
            }
            const float badd = (m == 0) ? b_rel0[col] : 0.f;
            #pragma unroll
            for (int reg = 0; reg < 4; ++reg)
                ABm[m][(g * 4 + reg) * 132 + col] = acc[reg] + badd;
        }
    }
    __syncthreads();

    // ---- P4b: rel pass -> T, cnt ----
    {
        f32x4 acc[4];
        #pragma unroll
        for (int nt = 0; nt < 4; ++nt) {
            const float b1 = b_rel1[nt * 16 + (lane & 15)];
            acc[nt] = {b1, b1, b1, b1};
        }
        #pragma unroll
        for (int kg = 0; kg < 4; ++kg) {
            s16x8 ah, al;
            x1frag(Arow, Brow, &wdl[0][0], dpair, kg * 32 + g * 8, ah, al);
            #pragma unroll
            for (int nt = 0; nt < 4; ++nt) {
                const s16x8 bh = wp[OFF_R1 + (kg * 4 + nt) * 64 + lane];
                const s16x8 bl = wp[OFF_R1 + 1024 + (kg * 4 + nt) * 64 + lane];
                acc[nt] = MFMA(ah, bh, acc[nt], 0, 0, 0);
                acc[nt] = MFMA(ah, bl, acc[nt], 0, 0, 0);
                acc[nt] = MFMA(al, bh, acc[nt], 0, 0, 0);
            }
        }
        // masked-attention coefficients; rows owned by (g, reg)
        const int ifull = ihalf * 4 + 2 * mt + (g >> 1);
        float coef[4], cpart = 0.f;
        #pragma unroll
        for (int reg = 0; reg < 4; ++reg) {
            const int jj = 4 * (g & 1) + reg;
            coef[reg] = (jj == ifull) ? 0.f : attreg[reg];
            cpart += coef[reg];
        }
        const float csum = cpart + __shfl_xor(cpart, 16, 64);
        if (((g & 1) == 0) && ((lane & 15) == 0))
            cntl[bi * 8 + ifull] = csum;
        #pragma unroll
        for (int nt = 0; nt < 4; ++nt) {
            float tpart = 0.f;
            #pragma unroll
            for (int reg = 0; reg < 4; ++reg)
                tpart += coef[reg] * elu_f(acc[nt][reg]);
            const float tsum = tpart + __shfl_xor(tpart, 16, 64);
            if ((g & 1) == 0)
                Tb[(bi * 8 + ifull) * 68 + nt * 16 + (lane & 15)] = tsum;
        }
    }
    __syncthreads();

    // ---- P5: U[b] = sum_i T[i] (into dead encb region) ----
    if (tid < 128) {
        const int b = tid >> 6, c = tid & 63;
        float u = 0.f;
        #pragma unroll
        for (int i = 0; i < 8; ++i) u += Tb[(b * 8 + i) * 68 + c];
        Ubuf[b * 68 + c] = u;
    }
    __syncthreads();

    // ---- P6: R = U2 @ W_rel2 via MFMA (waves 0-3) ----
    if (w < 4) {
        const int nt2 = w;
        f32x4 acc = {0.f, 0.f, 0.f, 0.f};
        const int row = lane & 15;
        #pragma unroll
        for (int kg = 0; kg < 2; ++kg) {
            float4 q0 = {0.f, 0.f, 0.f, 0.f}, q1 = {0.f, 0.f, 0.f, 0.f};
            if (row < 2) {
                q0 = *(const float4*)(Ubuf + row * 68 + kg * 32 + g * 8);
                q1 = *(const float4*)(Ubuf + row * 68 + kg * 32 + g * 8 + 4);
            }
            const float v[8] = {q0.x, q0.y, q0.z, q0.w, q1.x, q1.y, q1.z, q1.w};
            s16x8 uh, ul;
            splitpack8(v, uh, ul);
            const s16x8 bh = wp[OFF_R2 + (kg * 4 + nt2) * 64 + lane];
            const s16x8 bl = wp[OFF_R2 + 512 + (kg * 4 + nt2) * 64 + lane];
            acc = MFMA(uh, bh, acc, 0, 0, 0);
            acc = MFMA(uh, bl, acc, 0, 0, 0);
            acc = MFMA(ul, bh, acc, 0, 0, 0);
        }
        if (g == 0) {
            #pragma unroll
            for (int reg = 0; reg < 2; ++reg)
                Rbuf[reg * 64 + nt2 * 16 + (lane & 15)] = acc[reg];
        }
    }
    __syncthreads();

    // ---- P7: Out = sum_i sd + R + C*b_rel2 + U ----
    if (tid < 128) {
        const int b = tid >> 6, c = tid & 63;
        float sds = 0.f, C = 0.f;
        #pragma unroll
        for (int i = 0; i < 8; ++i) {
            sds += sd[(b * 8 + i) * 68 + c];
            C   += cntl[b * 8 + i];
        }
        Out[(size_t)(b0 + b) * 64 + c] = sds + Rbuf[b * 64 + c] + C * b_rel2[c] + Ubuf[b * 68 + c];
    }
}

extern "C" void kernel_launch(void* const* d_in, const int* in_sizes, int n_in,
                              void* d_out, int out_size, void* d_ws, size_t ws_size,
                              hipStream_t stream) {
    const float* S       = (const float*)d_in[0];
    const float* W_enc   = (const float*)d_in[1];
    const float* b_enc   = (const float*)d_in[2];
    const float* W_self0 = (const float*)d_in[3];
    const float* b_self0 = (const float*)d_in[4];
    const float* W_self1 = (const float*)d_in[5];
    const float* b_self1 = (const float*)d_in[6];
    const float* W_rel0  = (const float*)d_in[7];
    const float* b_rel0  = (const float*)d_in[8];
    const float* W_rel1  = (const float*)d_in[9];
    const float* b_rel1  = (const float*)d_in[10];
    const float* W_rel2  = (const float*)d_in[11];
    const float* b_rel2  = (const float*)d_in[12];
    const float* W_att0  = (const float*)d_in[13];
    const float* b_att0  = (const float*)d_in[14];
    const float* W_att1  = (const float*)d_in[15];
    const float* b_att1  = (const float*)d_in[16];
    const float* W_att2  = (const float*)d_in[17];
    const float* b_att2  = (const float*)d_in[18];

    s16x8* wpk = (s16x8*)d_ws;

    prep_kernel<<<dim3(128), dim3(64), 0, stream>>>(
        W_enc, W_self0, W_self1, W_rel0, W_att0, W_att1, W_rel1, W_rel2, wpk);

    const int nB   = in_sizes[0] / (NN * NCL);   // 8192
    const int grid = nB / NG;                    // 4096

    gh_kernel<<<dim3(grid), dim3(NT), 0, stream>>>(
        S, b_enc, b_self0, b_self1,
        W_rel0, b_rel0, b_rel1, b_rel2,
        W_att0, b_att0, b_att1, W_att2, b_att2,
        wpk, (float*)d_out);
}

// Round 8
// 221.660 us; speedup vs baseline: 1.0827x; 1.0827x over previous
//
#include <hip/hip_runtime.h>
#include <math.h>

constexpr int NCL = 64;
constexpr int NN  = 8;
constexpr int NG  = 2;      // batch elems per block
constexpr int NT  = 512;    // 8 waves

typedef __attribute__((ext_vector_type(4))) float f32x4;
typedef __attribute__((ext_vector_type(2))) float f32x2;
typedef __attribute__((ext_vector_type(8))) short s16x8;
#define MFMA __builtin_amdgcn_mfma_f32_16x16x32_bf16

// workspace layout offsets (units of s16x8 = 16 B)
constexpr int OFF_ENC = 0;      // 8 frags  (hi 512 | lo 512)
constexpr int OFF_S0  = 1024;
constexpr int OFF_S1  = 2048;
constexpr int OFF_R0  = 3072;   // 32 frags (hi 2048 | lo 2048)
constexpr int OFF_A0  = 7168;
constexpr int OFF_A1  = 11264;  // 16 frags (hi 1024 | lo 1024)
constexpr int OFF_R1  = 13312;
constexpr int OFF_R2  = 15360;  // 8 frags  (hi 512 | lo 512)

__device__ __forceinline__ float elu_f(float x) { return x > 0.f ? x : __expf(x) - 1.f; }

__device__ __forceinline__ unsigned f2u(float x) { union { float f; unsigned u; } c; c.f = x; return c.u; }
__device__ __forceinline__ float u2f(unsigned u) { union { unsigned u; float f; } c; c.u = u; return c.f; }

// Pack 8 fp32 -> bf16 hi (truncated) + bf16 lo (truncated residual) fragments.
__device__ __forceinline__ void splitpack8(const float v[8], s16x8& hi, s16x8& lo) {
    union { s16x8 s; unsigned u[4]; } H, L;
    #pragma unroll
    for (int e = 0; e < 8; e += 2) {
        H.u[e >> 1] = __builtin_amdgcn_perm(f2u(v[e + 1]), f2u(v[e]), 0x07060302u);
        f32x2 t = {u2f(f2u(v[e]) & 0xffff0000u), u2f(f2u(v[e + 1]) & 0xffff0000u)};
        f32x2 r = (f32x2){v[e], v[e + 1]} - t;          // v_pk_add_f32
        L.u[e >> 1] = __builtin_amdgcn_perm(f2u(r.y), f2u(r.x), 0x07060302u);
    }
    hi = H.s; lo = L.s;
}

// A-fragment (split hi/lo) from fp32 LDS activations, row stride 68.
__device__ __forceinline__ void afrag_split(const float* act, int row, int kbase,
                                            s16x8& hi, s16x8& lo) {
    const float4 v0 = *(const float4*)(act + row * 68 + kbase);
    const float4 v1 = *(const float4*)(act + row * 68 + kbase + 4);
    const float v[8] = {v0.x, v0.y, v0.z, v0.w, v1.x, v1.y, v1.z, v1.w};
    splitpack8(v, hi, lo);
}

// 16x16 tile of act[16x64] @ W[64x64] from packed fragments (8-frag matrix).
__device__ __forceinline__ f32x4 node_tile_pk(const float* act, const s16x8* __restrict__ wb,
                                              int mt, int nt, int lane) {
    const int row = mt * 16 + (lane & 15);
    const int g   = lane >> 4;
    f32x4 acc = {0.f, 0.f, 0.f, 0.f};
    #pragma unroll
    for (int kg = 0; kg < 2; ++kg) {
        s16x8 ah, al;
        afrag_split(act, row, kg * 32 + g * 8, ah, al);
        const s16x8 bh = wb[(kg * 4 + nt) * 64 + lane];
        const s16x8 bl = wb[512 + (kg * 4 + nt) * 64 + lane];
        acc = MFMA(ah, bh, acc, 0, 0, 0);
        acc = MFMA(ah, bl, acc, 0, 0, 0);
        acc = MFMA(al, bh, acc, 0, 0, 0);
    }
    return acc;
}

// X1 pair-feature fragment with packed-fp32 math:
// elu(A[f] + B[f] + d*wd[f]) for f = fbase..fbase+7
__device__ __forceinline__ void x1frag(const float* Arow, const float* Brow,
                                       const float* wdg, float d, int fbase,
                                       s16x8& hi, s16x8& lo) {
    const float4 a0 = *(const float4*)(Arow + fbase);
    const float4 a1 = *(const float4*)(Arow + fbase + 4);
    const float4 c0 = *(const float4*)(Brow + fbase);
    const float4 c1 = *(const float4*)(Brow + fbase + 4);
    const float4 w0 = *(const float4*)(wdg + fbase);
    const float4 w1 = *(const float4*)(wdg + fbase + 4);
    const f32x2 A2[4] = {{a0.x, a0.y}, {a0.z, a0.w}, {a1.x, a1.y}, {a1.z, a1.w}};
    const f32x2 C2[4] = {{c0.x, c0.y}, {c0.z, c0.w}, {c1.x, c1.y}, {c1.z, c1.w}};
    const f32x2 W2[4] = {{w0.x, w0.y}, {w0.z, w0.w}, {w1.x, w1.y}, {w1.z, w1.w}};
    const f32x2 dd = {d, d};
    union { s16x8 s; unsigned u[4]; } H, L;
    #pragma unroll
    for (int p = 0; p < 4; ++p) {
        const f32x2 t = __builtin_elementwise_fma(dd, W2[p], A2[p] + C2[p]); // pk_add + pk_fma
        const float v0 = elu_f(t.x), v1 = elu_f(t.y);
        H.u[p] = __builtin_amdgcn_perm(f2u(v1), f2u(v0), 0x07060302u);
        const f32x2 tr = {u2f(f2u(v0) & 0xffff0000u), u2f(f2u(v1) & 0xffff0000u)};
        const f32x2 r  = (f32x2){v0, v1} - tr;                               // pk_add
        L.u[p] = __builtin_amdgcn_perm(f2u(r.y), f2u(r.x), 0x07060302u);
    }
    hi = H.s; lo = L.s;
}

// ---------------- prep: pack weights into split-bf16 fragment planes ----------------
__device__ __forceinline__ short bfh_rn(float x) {
    union { float f; unsigned u; } c; c.f = x;
    return (short)((c.u + 0x7fffu + ((c.u >> 16) & 1u)) >> 16);
}
__device__ __forceinline__ void split_tr(float x, short& hi, short& lo) {
    union { float f; unsigned u; } c; c.f = x;
    hi = (short)(c.u >> 16);
    union { unsigned u; float f; } t; t.u = c.u & 0xffff0000u;
    lo = bfh_rn(x - t.f);
}

__global__ __launch_bounds__(64)
void prep_kernel(const float* __restrict__ We,  const float* __restrict__ Ws0,
                 const float* __restrict__ Ws1, const float* __restrict__ Wr0,
                 const float* __restrict__ Wa0, const float* __restrict__ Wa1,
                 const float* __restrict__ Wr1, const float* __restrict__ Wr2,
                 s16x8* __restrict__ ws)
{
    const int b = blockIdx.x, lane = threadIdx.x;
    const float* W; int nnt, nfrag, base, frag;
    if      (b < 8)   { W = We;  nnt = 4; nfrag = 8;  base = OFF_ENC; frag = b; }
    else if (b < 16)  { W = Ws0; nnt = 4; nfrag = 8;  base = OFF_S0;  frag = b - 8; }
    else if (b < 24)  { W = Ws1; nnt = 4; nfrag = 8;  base = OFF_S1;  frag = b - 16; }
    else if (b < 56)  { W = Wr0; nnt = 8; nfrag = 32; base = OFF_R0;  frag = b - 24; }
    else if (b < 88)  { W = Wa0; nnt = 8; nfrag = 32; base = OFF_A0;  frag = b - 56; }
    else if (b < 104) { W = Wa1; nnt = 4; nfrag = 16; base = OFF_A1;  frag = b - 88; }
    else if (b < 120) { W = Wr1; nnt = 4; nfrag = 16; base = OFF_R1;  frag = b - 104; }
    else              { W = Wr2; nnt = 4; nfrag = 8;  base = OFF_R2;  frag = b - 120; }
    const int kg = frag / nnt, nt = frag % nnt;
    const int N  = nnt * 16;
    const int g  = lane >> 4, col = nt * 16 + (lane & 15);
    s16x8 hi, lo;
    #pragma unroll
    for (int e = 0; e < 8; ++e) {
        short a, c; split_tr(W[(kg * 32 + g * 8 + e) * N + col], a, c);
        hi[e] = a; lo[e] = c;
    }
    ws[base + frag * 64 + lane]              = hi;
    ws[base + nfrag * 64 + frag * 64 + lane] = lo;
}

// ---------------- main ----------------
__global__ __launch_bounds__(NT, 6)
void gh_kernel(const float* __restrict__ S,
               const float* __restrict__ b_enc,
               const float* __restrict__ b_self0, const float* __restrict__ b_self1,
               const float* __restrict__ W_rel0,  const float* __restrict__ b_rel0,
               const float* __restrict__ b_rel1,  const float* __restrict__ b_rel2,
               const float* __restrict__ W_att0,  const float* __restrict__ b_att0,
               const float* __restrict__ b_att1,
               const float* __restrict__ W_att2,  const float* __restrict__ b_att2,
               const s16x8* __restrict__ wp,
               float* __restrict__ Out)
{
    // LDS: 3*4352 + 2*8448 + 512 + 64 + 1024 = 31,552 B  -> 4-5 blocks/CU (wave cap 4)
    __shared__ __align__(16) float sbuf[16 * 68];    // s; later self_dyn
    __shared__ __align__(16) float encb[16 * 68];    // enc; later Ubuf/Rbuf
    __shared__ __align__(16) float hbuf[16 * 68];    // h; later Tbuf
    __shared__ __align__(16) float ABm[2][16 * 132]; // reused: att A/B, then rel A/B
    __shared__ float d2l[2 * 64];
    __shared__ float cntl[16];
    __shared__ float wdl[2][128];                    // dist rows: 0 rel, 1 att

    const int tid  = threadIdx.x;
    const int w    = tid >> 6;
    const int lane = tid & 63;
    const int g    = lane >> 4;
    const int b0   = blockIdx.x * NG;
    float* sd   = sbuf;
    float* Tb   = hbuf;
    float* Ubuf = encb;        // [2][68]
    float* Rbuf = encb + 512;  // [2][64]

    // ---- P0: load s, dist rows ----
    {
        const float* src = S + (size_t)b0 * NN * NCL;
        for (int idx = tid; idx < 16 * 64; idx += NT)
            sbuf[(idx >> 6) * 68 + (idx & 63)] = src[idx];
        if (tid < 128) {
            wdl[0][tid] = W_rel0[128 * 128 + tid];
            wdl[1][tid] = W_att0[128 * 128 + tid];
        }
    }
    __syncthreads();

    if (tid < 128) {
        const int bi = tid >> 6, i = (tid >> 3) & 7, j = tid & 7;
        const float dx = sbuf[(bi * 8 + i) * 68 + 0] - sbuf[(bi * 8 + j) * 68 + 0];
        const float dy = sbuf[(bi * 8 + i) * 68 + 1] - sbuf[(bi * 8 + j) * 68 + 1];
        d2l[bi * 64 + i * 8 + j] = dx * dx + dy * dy;
    }

    // ---- P1: enc (waves 0-3) ----
    if (w < 4) {
        const int nt = w;
        f32x4 acc = node_tile_pk(sbuf, wp + OFF_ENC, 0, nt, lane);
        const int   col = nt * 16 + (lane & 15);
        const float be  = b_enc[col];
        #pragma unroll
        for (int reg = 0; reg < 4; ++reg) {
            const int row = g * 4 + reg;
            float v = acc[reg] + be;
            if (col < 2) v = sbuf[row * 68 + col];
            encb[row * 68 + col] = v;
        }
    }
    __syncthreads();

    // ---- P2: h = elu(enc @ W_self0 + b) (waves 0-3) ----
    if (w < 4) {
        const int nt = w;
        f32x4 acc = node_tile_pk(encb, wp + OFF_S0, 0, nt, lane);
        const int   col = nt * 16 + (lane & 15);
        const float bs  = b_self0[col];
        #pragma unroll
        for (int reg = 0; reg < 4; ++reg)
            hbuf[(g * 4 + reg) * 68 + col] = elu_f(acc[reg] + bs);
    }
    __syncthreads();

    // ---- P3a: self1 (waves 0-3) + att pair projections (all 8 waves) ----
    if (w < 4) {
        const int nt = w;
        f32x4 acc = node_tile_pk(hbuf, wp + OFF_S1, 0, nt, lane);
        const int   col = nt * 16 + (lane & 15);
        const float bs  = b_self1[col];
        #pragma unroll
        for (int reg = 0; reg < 4; ++reg) {
            const int row = g * 4 + reg;
            sd[row * 68 + col] = acc[reg] + bs + hbuf[row * 68 + col];
        }
    }
    {
        const int ntp = w;
        const int row = lane & 15;
        const int col = ntp * 16 + (lane & 15);
        s16x8 eh[2], el[2];
        afrag_split(encb, row, g * 8, eh[0], el[0]);
        afrag_split(encb, row, 32 + g * 8, eh[1], el[1]);
        #pragma unroll
        for (int m = 0; m < 2; ++m) {               // 0: A_att, 1: B_att
            const int kgo = m * 2;
            f32x4 acc = {0.f, 0.f, 0.f, 0.f};
            #pragma unroll
            for (int kg = 0; kg < 2; ++kg) {
                const s16x8 bh = wp[OFF_A0 + ((kgo + kg) * 8 + ntp) * 64 + lane];
                const s16x8 bl = wp[OFF_A0 + 2048 + ((kgo + kg) * 8 + ntp) * 64 + lane];
                acc = MFMA(eh[kg], bh, acc, 0, 0, 0);
                acc = MFMA(eh[kg], bl, acc, 0, 0, 0);
                acc = MFMA(el[kg], bh, acc, 0, 0, 0);
            }
            const float badd = (m == 0) ? b_att0[col] : 0.f;
            #pragma unroll
            for (int reg = 0; reg < 4; ++reg)
                ABm[m][(g * 4 + reg) * 132 + col] = acc[reg] + badd;
        }
    }
    __syncthreads();

    // ---- P4a: attention pass ----
    const int bi    = w >> 2;
    const int ihalf = (w >> 1) & 1;
    const int mt    = w & 1;
    const int pp    = (lane & 15) + 16 * mt;
    const int il    = pp >> 3, jj8 = pp & 7;
    const float* Arow = &ABm[0][(bi * 8 + ihalf * 4 + il) * 132];
    const float* Brow = &ABm[1][(bi * 8 + jj8) * 132];
    const float dpair = d2l[bi * 64 + (ihalf * 4 + il) * 8 + jj8];

    float attreg[4];
    {
        const float ba2 = b_att2[0];
        float wa2v[4];
        f32x4 acc[4];
        #pragma unroll
        for (int nt = 0; nt < 4; ++nt) {
            wa2v[nt] = W_att2[nt * 16 + (lane & 15)];
            const float b1 = b_att1[nt * 16 + (lane & 15)];
            acc[nt] = {b1, b1, b1, b1};
        }
        #pragma unroll
        for (int kg = 0; kg < 4; ++kg) {
            s16x8 ah, al;
            x1frag(Arow, Brow, &wdl[1][0], dpair, kg * 32 + g * 8, ah, al);
            #pragma unroll
            for (int nt = 0; nt < 4; ++nt) {
                const s16x8 bh = wp[OFF_A1 + (kg * 4 + nt) * 64 + lane];
                const s16x8 bl = wp[OFF_A1 + 1024 + (kg * 4 + nt) * 64 + lane];
                acc[nt] = MFMA(ah, bh, acc[nt], 0, 0, 0);
                acc[nt] = MFMA(ah, bl, acc[nt], 0, 0, 0);
                acc[nt] = MFMA(al, bh, acc[nt], 0, 0, 0);
            }
        }
        #pragma unroll
        for (int reg = 0; reg < 4; ++reg) {
            float s = 0.f;
            #pragma unroll
            for (int nt = 0; nt < 4; ++nt) s += elu_f(acc[nt][reg]) * wa2v[nt];
            s += __shfl_xor(s, 1, 64);
            s += __shfl_xor(s, 2, 64);
            s += __shfl_xor(s, 4, 64);
            s += __shfl_xor(s, 8, 64);
            attreg[reg] = 1.f / (1.f + __expf(-(s + ba2)));
        }
    }
    __syncthreads();   // everyone done reading att ABm

    // ---- P3b: rel pair projections into the same buffer ----
    {
        const int ntp = w;
        const int row = lane & 15;
        const int col = ntp * 16 + (lane & 15);
        s16x8 eh[2], el[2];
        afrag_split(encb, row, g * 8, eh[0], el[0]);
        afrag_split(encb, row, 32 + g * 8, eh[1], el[1]);
        #pragma unroll
        for (int m = 0; m < 2; ++m) {               // 0: A_rel, 1: B_rel
            const int kgo = m * 2;
            f32x4 acc = {0.f, 0.f, 0.f, 0.f};
            #pragma unroll
            for (int kg = 0; kg < 2; ++kg) {
                const s16x8 bh = wp[OFF_R0 + ((kgo + kg) * 8 + ntp) * 64 + lane];
                const s16x8 bl = wp[OFF_R0 + 2048 + ((kgo + kg) * 8 + ntp) * 64 + lane];
                acc = MFMA(eh[kg], bh, acc, 0, 0, 0);
                acc = MFMA(eh[kg], bl, acc, 0, 0, 0);
                acc = MFMA(el[kg], bh, acc, 0, 0, 0);
            }
            const float badd = (m == 0) ? b_rel0[col] : 0.f;
            #pragma unroll
            for (int reg = 0; reg < 4; ++reg)
                ABm[m][(g * 4 + reg) * 132 + col] = acc[reg] + badd;
        }
    }
    __syncthreads();

    // ---- P4b: rel pass -> T, cnt ----
    {
        f32x4 acc[4];
        #pragma unroll
        for (int nt = 0; nt < 4; ++nt) {
            const float b1 = b_rel1[nt * 16 + (lane & 15)];
            acc[nt] = {b1, b1, b1, b1};
        }
        #pragma unroll
        for (int kg = 0; kg < 4; ++kg) {
            s16x8 ah, al;
            x1frag(Arow, Brow, &wdl[0][0], dpair, kg * 32 + g * 8, ah, al);
            #pragma unroll
            for (int nt = 0; nt < 4; ++nt) {
                const s16x8 bh = wp[OFF_R1 + (kg * 4 + nt) * 64 + lane];
                const s16x8 bl = wp[OFF_R1 + 1024 + (kg * 4 + nt) * 64 + lane];
                acc[nt] = MFMA(ah, bh, acc[nt], 0, 0, 0);
                acc[nt] = MFMA(ah, bl, acc[nt], 0, 0, 0);
                acc[nt] = MFMA(al, bh, acc[nt], 0, 0, 0);
            }
        }
        // masked-attention coefficients; rows owned by (g, reg)
        const int ifull = ihalf * 4 + 2 * mt + (g >> 1);
        float coef[4], cpart = 0.f;
        #pragma unroll
        for (int reg = 0; reg < 4; ++reg) {
            const int jj = 4 * (g & 1) + reg;
            coef[reg] = (jj == ifull) ? 0.f : attreg[reg];
            cpart += coef[reg];
        }
        const float csum = cpart + __shfl_xor(cpart, 16, 64);
        if (((g & 1) == 0) && ((lane & 15) == 0))
            cntl[bi * 8 + ifull] = csum;
        #pragma unroll
        for (int nt = 0; nt < 4; ++nt) {
            float tpart = 0.f;
            #pragma unroll
            for (int reg = 0; reg < 4; ++reg)
                tpart += coef[reg] * elu_f(acc[nt][reg]);
            const float tsum = tpart + __shfl_xor(tpart, 16, 64);
            if ((g & 1) == 0)
                Tb[(bi * 8 + ifull) * 68 + nt * 16 + (lane & 15)] = tsum;
        }
    }
    __syncthreads();

    // ---- P5: U[b] = sum_i T[i] (into dead encb region) ----
    if (tid < 128) {
        const int b = tid >> 6, c = tid & 63;
        float u = 0.f;
        #pragma unroll
        for (int i = 0; i < 8; ++i) u += Tb[(b * 8 + i) * 68 + c];
        Ubuf[b * 68 + c] = u;
    }
    __syncthreads();

    // ---- P6: R = U2 @ W_rel2 via MFMA (waves 0-3) ----
    if (w < 4) {
        const int nt2 = w;
        f32x4 acc = {0.f, 0.f, 0.f, 0.f};
        const int row = lane & 15;
        #pragma unroll
        for (int kg = 0; kg < 2; ++kg) {
            float4 q0 = {0.f, 0.f, 0.f, 0.f}, q1 = {0.f, 0.f, 0.f, 0.f};
            if (row < 2) {
                q0 = *(const float4*)(Ubuf + row * 68 + kg * 32 + g * 8);
                q1 = *(const float4*)(Ubuf + row * 68 + kg * 32 + g * 8 + 4);
            }
            const float v[8] = {q0.x, q0.y, q0.z, q0.w, q1.x, q1.y, q1.z, q1.w};
            s16x8 uh, ul;
            splitpack8(v, uh, ul);
            const s16x8 bh = wp[OFF_R2 + (kg * 4 + nt2) * 64 + lane];
            const s16x8 bl = wp[OFF_R2 + 512 + (kg * 4 + nt2) * 64 + lane];
            acc = MFMA(uh, bh, acc, 0, 0, 0);
            acc = MFMA(uh, bl, acc, 0, 0, 0);
            acc = MFMA(ul, bh, acc, 0, 0, 0);
        }
        if (g == 0) {
            #pragma unroll
            for (int reg = 0; reg < 2; ++reg)
                Rbuf[reg * 64 + nt2 * 16 + (lane & 15)] = acc[reg];
        }
    }
    __syncthreads();

    // ---- P7: Out = sum_i sd + R + C*b_rel2 + U ----
    if (tid < 128) {
        const int b = tid >> 6, c = tid & 63;
        float sds = 0.f, C = 0.f;
        #pragma unroll
        for (int i = 0; i < 8; ++i) {
            sds += sd[(b * 8 + i) * 68 + c];
            C   += cntl[b * 8 + i];
        }
        Out[(size_t)(b0 + b) * 64 + c] = sds + Rbuf[b * 64 + c] + C * b_rel2[c] + Ubuf[b * 68 + c];
    }
}

extern "C" void kernel_launch(void* const* d_in, const int* in_sizes, int n_in,
                              void* d_out, int out_size, void* d_ws, size_t ws_size,
                              hipStream_t stream) {
    const float* S       = (const float*)d_in[0];
    const float* W_enc   = (const float*)d_in[1];
    const float* b_enc   = (const float*)d_in[2];
    const float* W_self0 = (const float*)d_in[3];
    const float* b_self0 = (const float*)d_in[4];
    const float* W_self1 = (const float*)d_in[5];
    const float* b_self1 = (const float*)d_in[6];
    const float* W_rel0  = (const float*)d_in[7];
    const float* b_rel0  = (const float*)d_in[8];
    const float* W_rel1  = (const float*)d_in[9];
    const float* b_rel1  = (const float*)d_in[10];
    const float* W_rel2  = (const float*)d_in[11];
    const float* b_rel2  = (const float*)d_in[12];
    const float* W_att0  = (const float*)d_in[13];
    const float* b_att0  = (const float*)d_in[14];
    const float* W_att1  = (const float*)d_in[15];
    const float* b_att1  = (const float*)d_in[16];
    const float* W_att2  = (const float*)d_in[17];
    const float* b_att2  = (const float*)d_in[18];

    s16x8* wpk = (s16x8*)d_ws;

    prep_kernel<<<dim3(128), dim3(64), 0, stream>>>(
        W_enc, W_self0, W_self1, W_rel0, W_att0, W_att1, W_rel1, W_rel2, wpk);

    const int nB   = in_sizes[0] / (NN * NCL);   // 8192
    const int grid = nB / NG;                    // 4096

    gh_kernel<<<dim3(grid), dim3(NT), 0, stream>>>(
        S, b_enc, b_self0, b_self1,
        W_rel0, b_rel0, b_rel1, b_rel2,
        W_att0, b_att0, b_att1, W_att2, b_att2,
        wpk, (float*)d_out);
}

// Round 9
// 211.813 us; speedup vs baseline: 1.1330x; 1.0465x over previous
//
#include <hip/hip_runtime.h>
#include <math.h>

constexpr int NCL = 64;
constexpr int NN  = 8;
constexpr int NG  = 2;      // batch elems per block
constexpr int NT  = 512;    // 8 waves

typedef __attribute__((ext_vector_type(4))) float f32x4;
typedef __attribute__((ext_vector_type(2))) float f32x2;
typedef __attribute__((ext_vector_type(8))) short s16x8;
#define MFMA __builtin_amdgcn_mfma_f32_16x16x32_bf16

// workspace layout offsets (units of s16x8 = 16 B)
constexpr int OFF_ENC = 0;      // 8 frags  (hi 512 | lo 512)
constexpr int OFF_S0  = 1024;
constexpr int OFF_S1  = 2048;
constexpr int OFF_R0  = 3072;   // 32 frags (hi 2048 | lo 2048)
constexpr int OFF_A0  = 7168;
constexpr int OFF_A1  = 11264;  // 16 frags (hi 1024 | lo 1024)
constexpr int OFF_R1  = 13312;
constexpr int OFF_R2  = 15360;  // 8 frags  (hi 512 | lo 512)

__device__ __forceinline__ float elu_f(float x) { return x > 0.f ? x : __expf(x) - 1.f; }

__device__ __forceinline__ unsigned f2u(float x) { union { float f; unsigned u; } c; c.f = x; return c.u; }
__device__ __forceinline__ float u2f(unsigned u) { union { unsigned u; float f; } c; c.u = u; return c.f; }

// Pack 8 fp32 -> bf16 hi (truncated) + bf16 lo (truncated residual) fragments.
__device__ __forceinline__ void splitpack8(const float v[8], s16x8& hi, s16x8& lo) {
    union { s16x8 s; unsigned u[4]; } H, L;
    #pragma unroll
    for (int e = 0; e < 8; e += 2) {
        H.u[e >> 1] = __builtin_amdgcn_perm(f2u(v[e + 1]), f2u(v[e]), 0x07060302u);
        f32x2 t = {u2f(f2u(v[e]) & 0xffff0000u), u2f(f2u(v[e + 1]) & 0xffff0000u)};
        f32x2 r = (f32x2){v[e], v[e + 1]} - t;          // v_pk_add_f32
        L.u[e >> 1] = __builtin_amdgcn_perm(f2u(r.y), f2u(r.x), 0x07060302u);
    }
    hi = H.s; lo = L.s;
}

// A-fragment (split hi/lo) from fp32 LDS activations, row stride 68.
__device__ __forceinline__ void afrag_split(const float* act, int row, int kbase,
                                            s16x8& hi, s16x8& lo) {
    const float4 v0 = *(const float4*)(act + row * 68 + kbase);
    const float4 v1 = *(const float4*)(act + row * 68 + kbase + 4);
    const float v[8] = {v0.x, v0.y, v0.z, v0.w, v1.x, v1.y, v1.z, v1.w};
    splitpack8(v, hi, lo);
}

// 16x16 tile of act[16x64] @ W[64x64] from packed fragments (8-frag matrix).
__device__ __forceinline__ f32x4 node_tile_pk(const float* act, const s16x8* __restrict__ wb,
                                              int mt, int nt, int lane) {
    const int row = mt * 16 + (lane & 15);
    const int g   = lane >> 4;
    f32x4 acc = {0.f, 0.f, 0.f, 0.f};
    #pragma unroll
    for (int kg = 0; kg < 2; ++kg) {
        s16x8 ah, al;
        afrag_split(act, row, kg * 32 + g * 8, ah, al);
        const s16x8 bh = wb[(kg * 4 + nt) * 64 + lane];
        const s16x8 bl = wb[512 + (kg * 4 + nt) * 64 + lane];
        acc = MFMA(ah, bh, acc, 0, 0, 0);
        acc = MFMA(ah, bl, acc, 0, 0, 0);
        acc = MFMA(al, bh, acc, 0, 0, 0);
    }
    return acc;
}

// Build one unit's X1 fragment from preloaded B/wd vectors + A row.
__device__ __forceinline__ void x1build(const float* Arow, int fbase,
                                        const float4 b0, const float4 b1,
                                        const float4 w0, const float4 w1, float d,
                                        s16x8& hi, s16x8& lo) {
    const float4 a0 = *(const float4*)(Arow + fbase);
    const float4 a1 = *(const float4*)(Arow + fbase + 4);
    const f32x2 A2[4] = {{a0.x, a0.y}, {a0.z, a0.w}, {a1.x, a1.y}, {a1.z, a1.w}};
    const f32x2 C2[4] = {{b0.x, b0.y}, {b0.z, b0.w}, {b1.x, b1.y}, {b1.z, b1.w}};
    const f32x2 W2[4] = {{w0.x, w0.y}, {w0.z, w0.w}, {w1.x, w1.y}, {w1.z, w1.w}};
    const f32x2 dd = {d, d};
    union { s16x8 s; unsigned u[4]; } H, L;
    #pragma unroll
    for (int p = 0; p < 4; ++p) {
        const f32x2 t = __builtin_elementwise_fma(dd, W2[p], A2[p] + C2[p]);
        const float v0 = elu_f(t.x), v1 = elu_f(t.y);
        H.u[p] = __builtin_amdgcn_perm(f2u(v1), f2u(v0), 0x07060302u);
        const f32x2 tr = {u2f(f2u(v0) & 0xffff0000u), u2f(f2u(v1) & 0xffff0000u)};
        const f32x2 r  = (f32x2){v0, v1} - tr;
        L.u[p] = __builtin_amdgcn_perm(f2u(r.y), f2u(r.x), 0x07060302u);
    }
    hi = H.s; lo = L.s;
}

// ---------------- prep: pack weights into split-bf16 fragment planes ----------------
__device__ __forceinline__ short bfh_rn(float x) {
    union { float f; unsigned u; } c; c.f = x;
    return (short)((c.u + 0x7fffu + ((c.u >> 16) & 1u)) >> 16);
}
__device__ __forceinline__ void split_tr(float x, short& hi, short& lo) {
    union { float f; unsigned u; } c; c.f = x;
    hi = (short)(c.u >> 16);
    union { unsigned u; float f; } t; t.u = c.u & 0xffff0000u;
    lo = bfh_rn(x - t.f);
}

__global__ __launch_bounds__(64)
void prep_kernel(const float* __restrict__ We,  const float* __restrict__ Ws0,
                 const float* __restrict__ Ws1, const float* __restrict__ Wr0,
                 const float* __restrict__ Wa0, const float* __restrict__ Wa1,
                 const float* __restrict__ Wr1, const float* __restrict__ Wr2,
                 s16x8* __restrict__ ws)
{
    const int b = blockIdx.x, lane = threadIdx.x;
    const float* W; int nnt, nfrag, base, frag;
    if      (b < 8)   { W = We;  nnt = 4; nfrag = 8;  base = OFF_ENC; frag = b; }
    else if (b < 16)  { W = Ws0; nnt = 4; nfrag = 8;  base = OFF_S0;  frag = b - 8; }
    else if (b < 24)  { W = Ws1; nnt = 4; nfrag = 8;  base = OFF_S1;  frag = b - 16; }
    else if (b < 56)  { W = Wr0; nnt = 8; nfrag = 32; base = OFF_R0;  frag = b - 24; }
    else if (b < 88)  { W = Wa0; nnt = 8; nfrag = 32; base = OFF_A0;  frag = b - 56; }
    else if (b < 104) { W = Wa1; nnt = 4; nfrag = 16; base = OFF_A1;  frag = b - 88; }
    else if (b < 120) { W = Wr1; nnt = 4; nfrag = 16; base = OFF_R1;  frag = b - 104; }
    else              { W = Wr2; nnt = 4; nfrag = 8;  base = OFF_R2;  frag = b - 120; }
    const int kg = frag / nnt, nt = frag % nnt;
    const int N  = nnt * 16;
    const int g  = lane >> 4, col = nt * 16 + (lane & 15);
    s16x8 hi, lo;
    #pragma unroll
    for (int e = 0; e < 8; ++e) {
        short a, c; split_tr(W[(kg * 32 + g * 8 + e) * N + col], a, c);
        hi[e] = a; lo[e] = c;
    }
    ws[base + frag * 64 + lane]              = hi;
    ws[base + nfrag * 64 + frag * 64 + lane] = lo;
}

// ---------------- main ----------------
__global__ __launch_bounds__(NT, 6)
void gh_kernel(const float* __restrict__ S,
               const float* __restrict__ b_enc,
               const float* __restrict__ b_self0, const float* __restrict__ b_self1,
               const float* __restrict__ W_rel0,  const float* __restrict__ b_rel0,
               const float* __restrict__ b_rel1,  const float* __restrict__ b_rel2,
               const float* __restrict__ W_att0,  const float* __restrict__ b_att0,
               const float* __restrict__ b_att1,
               const float* __restrict__ W_att2,  const float* __restrict__ b_att2,
               const s16x8* __restrict__ wp,
               float* __restrict__ Out)
{
    // LDS: 3*4352 + 33792 + 512 + 64 + 1024 + 256 = 48,704 B -> 3 blocks/CU
    __shared__ __align__(16) float sbuf[16 * 68];    // s; later self_dyn
    __shared__ __align__(16) float encb[16 * 68];    // enc; later Ubuf/Rbuf
    __shared__ __align__(16) float hbuf[16 * 68];    // h; later Tbuf
    __shared__ __align__(16) float ABm[4][16 * 132]; // 0:Ar 1:Br 2:Aa 3:Ba
    __shared__ float d2l[2 * 64];
    __shared__ float cntl[16];
    __shared__ float wdl[2][128];                    // dist rows: 0 rel, 1 att
    __shared__ __align__(16) float attl[2][8][8];    // masked att, [bi][i][j]

    const int tid  = threadIdx.x;
    const int w    = tid >> 6;
    const int lane = tid & 63;
    const int g    = lane >> 4;
    const int b0   = blockIdx.x * NG;
    float* sd   = sbuf;
    float* Tb   = hbuf;
    float* Ubuf = encb;        // [2][68]
    float* Rbuf = encb + 512;  // [2][64]

    // ---- P0: load s, dist rows ----
    {
        const float* src = S + (size_t)b0 * NN * NCL;
        for (int idx = tid; idx < 16 * 64; idx += NT)
            sbuf[(idx >> 6) * 68 + (idx & 63)] = src[idx];
        if (tid < 128) {
            wdl[0][tid] = W_rel0[128 * 128 + tid];
            wdl[1][tid] = W_att0[128 * 128 + tid];
        }
    }
    __syncthreads();

    if (tid < 128) {
        const int bi = tid >> 6, i = (tid >> 3) & 7, j = tid & 7;
        const float dx = sbuf[(bi * 8 + i) * 68 + 0] - sbuf[(bi * 8 + j) * 68 + 0];
        const float dy = sbuf[(bi * 8 + i) * 68 + 1] - sbuf[(bi * 8 + j) * 68 + 1];
        d2l[bi * 64 + i * 8 + j] = dx * dx + dy * dy;
    }

    // ---- P1: enc (waves 0-3) ----
    if (w < 4) {
        const int nt = w;
        f32x4 acc = node_tile_pk(sbuf, wp + OFF_ENC, 0, nt, lane);
        const int   col = nt * 16 + (lane & 15);
        const float be  = b_enc[col];
        #pragma unroll
        for (int reg = 0; reg < 4; ++reg) {
            const int row = g * 4 + reg;
            float v = acc[reg] + be;
            if (col < 2) v = sbuf[row * 68 + col];
            encb[row * 68 + col] = v;
        }
    }
    __syncthreads();

    // ---- P2: h = elu(enc @ W_self0 + b) (waves 0-3) ----
    if (w < 4) {
        const int nt = w;
        f32x4 acc = node_tile_pk(encb, wp + OFF_S0, 0, nt, lane);
        const int   col = nt * 16 + (lane & 15);
        const float bs  = b_self0[col];
        #pragma unroll
        for (int reg = 0; reg < 4; ++reg)
            hbuf[(g * 4 + reg) * 68 + col] = elu_f(acc[reg] + bs);
    }
    __syncthreads();

    // ---- P3: self1 (waves 0-3) + all pair projections (all 8 waves) ----
    if (w < 4) {
        const int nt = w;
        f32x4 acc = node_tile_pk(hbuf, wp + OFF_S1, 0, nt, lane);
        const int   col = nt * 16 + (lane & 15);
        const float bs  = b_self1[col];
        #pragma unroll
        for (int reg = 0; reg < 4; ++reg) {
            const int row = g * 4 + reg;
            sd[row * 68 + col] = acc[reg] + bs + hbuf[row * 68 + col];
        }
    }
    {
        const int ntp = w;                       // 8 column tiles
        const int row = lane & 15;
        const int col = ntp * 16 + (lane & 15);
        s16x8 eh[2], el[2];
        afrag_split(encb, row, g * 8, eh[0], el[0]);
        afrag_split(encb, row, 32 + g * 8, eh[1], el[1]);
        #pragma unroll
        for (int m = 0; m < 4; ++m) {
            const s16x8* wb = wp + ((m < 2) ? OFF_R0 : OFF_A0);
            const int kgo = (m & 1) * 2;
            f32x4 acc = {0.f, 0.f, 0.f, 0.f};
            #pragma unroll
            for (int kg = 0; kg < 2; ++kg) {
                const s16x8 bh = wb[((kgo + kg) * 8 + ntp) * 64 + lane];
                const s16x8 bl = wb[2048 + ((kgo + kg) * 8 + ntp) * 64 + lane];
                acc = MFMA(eh[kg], bh, acc, 0, 0, 0);
                acc = MFMA(eh[kg], bl, acc, 0, 0, 0);
                acc = MFMA(el[kg], bh, acc, 0, 0, 0);
            }
            const float badd = (m == 0) ? b_rel0[col] : (m == 2) ? b_att0[col] : 0.f;
            #pragma unroll
            for (int reg = 0; reg < 4; ++reg)
                ABm[m][(g * 4 + reg) * 132 + col] = acc[reg] + badd;
        }
    }
    __syncthreads();

    // ---- P4A: wave-specialized pair passes ----
    // waves 0-3: att pass (both mt units); waves 4-7: rel MFMA part (both mt units)
    const int isRel = w >> 2;
    const int wl    = w & 3;
    const int bi    = wl >> 1;
    const int ihalf = wl & 1;
    const int il0   = (lane & 15) >> 3;               // mt=0 A-row offset; mt=1 adds 2
    const int jj8   = lane & 7;
    const int mA    = isRel ? 0 : 2;                  // A matrix index
    const float* Arow0 = &ABm[mA][(bi * 8 + ihalf * 4 + il0) * 132];
    const float* Arow1 = Arow0 + 2 * 132;
    const float* Brow  = &ABm[mA + 1][(bi * 8 + jj8) * 132];
    const float* wdg   = &wdl[isRel ? 0 : 1][0];
    const float  d0    = d2l[bi * 64 + (ihalf * 4 + il0) * 8 + jj8];
    const float  d1    = d2l[bi * 64 + (ihalf * 4 + il0 + 2) * 8 + jj8];
    const s16x8* wfr   = wp + (isRel ? OFF_R1 : OFF_A1);

    f32x4 acc0[4], acc1[4];
    {
        const float* bias = isRel ? b_rel1 : b_att1;
        #pragma unroll
        for (int nt = 0; nt < 4; ++nt) {
            const float b1 = bias[nt * 16 + (lane & 15)];
            acc0[nt] = {b1, b1, b1, b1};
            acc1[nt] = {b1, b1, b1, b1};
        }
        #pragma unroll
        for (int kg = 0; kg < 4; ++kg) {
            const int fbase = kg * 32 + g * 8;
            const float4 c0 = *(const float4*)(Brow + fbase);
            const float4 c1 = *(const float4*)(Brow + fbase + 4);
            const float4 w0 = *(const float4*)(wdg + fbase);
            const float4 w1 = *(const float4*)(wdg + fbase + 4);
            s16x8 ah0, al0, ah1, al1;
            x1build(Arow0, fbase, c0, c1, w0, w1, d0, ah0, al0);
            x1build(Arow1, fbase, c0, c1, w0, w1, d1, ah1, al1);
            #pragma unroll
            for (int nt = 0; nt < 4; ++nt) {
                const s16x8 bh = wfr[(kg * 4 + nt) * 64 + lane];
                const s16x8 bl = wfr[1024 + (kg * 4 + nt) * 64 + lane];
                acc0[nt] = MFMA(ah0, bh, acc0[nt], 0, 0, 0);
                acc0[nt] = MFMA(ah0, bl, acc0[nt], 0, 0, 0);
                acc0[nt] = MFMA(al0, bh, acc0[nt], 0, 0, 0);
                acc1[nt] = MFMA(ah1, bh, acc1[nt], 0, 0, 0);
                acc1[nt] = MFMA(ah1, bl, acc1[nt], 0, 0, 0);
                acc1[nt] = MFMA(al1, bh, acc1[nt], 0, 0, 0);
            }
        }
    }

    if (!isRel) {
        // att epilogue: sigmoid, mask, write attl + cnt
        const float ba2 = b_att2[0];
        float wa2v[4];
        #pragma unroll
        for (int nt = 0; nt < 4; ++nt) wa2v[nt] = W_att2[nt * 16 + (lane & 15)];
        #pragma unroll
        for (int mt = 0; mt < 2; ++mt) {
            const f32x4* acc = mt ? acc1 : acc0;
            const int i = ihalf * 4 + 2 * mt + (g >> 1);
            float am[4], cpart = 0.f;
            #pragma unroll
            for (int reg = 0; reg < 4; ++reg) {
                float s = 0.f;
                #pragma unroll
                for (int nt = 0; nt < 4; ++nt) s += elu_f(acc[nt][reg]) * wa2v[nt];
                s += __shfl_xor(s, 1, 64);
                s += __shfl_xor(s, 2, 64);
                s += __shfl_xor(s, 4, 64);
                s += __shfl_xor(s, 8, 64);
                const float a = 1.f / (1.f + __expf(-(s + ba2)));
                const int jj  = 4 * (g & 1) + reg;
                am[reg] = (jj == i) ? 0.f : a;
                cpart  += am[reg];
            }
            const float csum = cpart + __shfl_xor(cpart, 16, 64);
            if ((lane & 15) == 0) {
                *(float4*)&attl[bi][i][4 * (g & 1)] = (float4){am[0], am[1], am[2], am[3]};
                if ((g & 1) == 0) cntl[bi * 8 + i] = csum;
            }
        }
    }
    __syncthreads();

    // ---- P4B: rel epilogue (waves 4-7) -> T ----
    if (isRel) {
        #pragma unroll
        for (int mt = 0; mt < 2; ++mt) {
            const f32x4* acc = mt ? acc1 : acc0;
            const int i = ihalf * 4 + 2 * mt + (g >> 1);
            const float4 cf = *(const float4*)&attl[bi][i][4 * (g & 1)];
            const float coef[4] = {cf.x, cf.y, cf.z, cf.w};
            #pragma unroll
            for (int nt = 0; nt < 4; ++nt) {
                float tpart = 0.f;
                #pragma unroll
                for (int reg = 0; reg < 4; ++reg)
                    tpart += coef[reg] * elu_f(acc[nt][reg]);
                const float tsum = tpart + __shfl_xor(tpart, 16, 64);
                if ((g & 1) == 0)
                    Tb[(bi * 8 + i) * 68 + nt * 16 + (lane & 15)] = tsum;
            }
        }
    }
    __syncthreads();

    // ---- P5: U[b] = sum_i T[i] (into dead encb region) ----
    if (tid < 128) {
        const int b = tid >> 6, c = tid & 63;
        float u = 0.f;
        #pragma unroll
        for (int i = 0; i < 8; ++i) u += Tb[(b * 8 + i) * 68 + c];
        Ubuf[b * 68 + c] = u;
    }
    __syncthreads();

    // ---- P6: R = U2 @ W_rel2 via MFMA (waves 0-3) ----
    if (w < 4) {
        const int nt2 = w;
        f32x4 acc = {0.f, 0.f, 0.f, 0.f};
        const int row = lane & 15;
        #pragma unroll
        for (int kg = 0; kg < 2; ++kg) {
            float4 q0 = {0.f, 0.f, 0.f, 0.f}, q1 = {0.f, 0.f, 0.f, 0.f};
            if (row < 2) {
                q0 = *(const float4*)(Ubuf + row * 68 + kg * 32 + g * 8);
                q1 = *(const float4*)(Ubuf + row * 68 + kg * 32 + g * 8 + 4);
            }
            const float v[8] = {q0.x, q0.y, q0.z, q0.w, q1.x, q1.y, q1.z, q1.w};
            s16x8 uh, ul;
            splitpack8(v, uh, ul);
            const s16x8 bh = wp[OFF_R2 + (kg * 4 + nt2) * 64 + lane];
            const s16x8 bl = wp[OFF_R2 + 512 + (kg * 4 + nt2) * 64 + lane];
            acc = MFMA(uh, bh, acc, 0, 0, 0);
            acc = MFMA(uh, bl, acc, 0, 0, 0);
            acc = MFMA(ul, bh, acc, 0, 0, 0);
        }
        if (g == 0) {
            #pragma unroll
            for (int reg = 0; reg < 2; ++reg)
                Rbuf[reg * 64 + nt2 * 16 + (lane & 15)] = acc[reg];
        }
    }
    __syncthreads();

    // ---- P7: Out = sum_i sd + R + C*b_rel2 + U ----
    if (tid < 128) {
        const int b = tid >> 6, c = tid & 63;
        float sds = 0.f, C = 0.f;
        #pragma unroll
        for (int i = 0; i < 8; ++i) {
            sds += sd[(b * 8 + i) * 68 + c];
            C   += cntl[b * 8 + i];
        }
        Out[(size_t)(b0 + b) * 64 + c] = sds + Rbuf[b * 64 + c] + C * b_rel2[c] + Ubuf[b * 68 + c];
    }
}

extern "C" void kernel_launch(void* const* d_in, const int* in_sizes, int n_in,
                              void* d_out, int out_size, void* d_ws, size_t ws_size,
                              hipStream_t stream) {
    const float* S       = (const float*)d_in[0];
    const float* W_enc   = (const float*)d_in[1];
    const float* b_enc   = (const float*)d_in[2];
    const float* W_self0 = (const float*)d_in[3];
    const float* b_self0 = (const float*)d_in[4];
    const float* W_self1 = (const float*)d_in[5];
    const float* b_self1 = (const float*)d_in[6];
    const float* W_rel0  = (const float*)d_in[7];
    const float* b_rel0  = (const float*)d_in[8];
    const float* W_rel1  = (const float*)d_in[9];
    const float* b_rel1  = (const float*)d_in[10];
    const float* W_rel2  = (const float*)d_in[11];
    const float* b_rel2  = (const float*)d_in[12];
    const float* W_att0  = (const float*)d_in[13];
    const float* b_att0  = (const float*)d_in[14];
    const float* W_att1  = (const float*)d_in[15];
    const float* b_att1  = (const float*)d_in[16];
    const float* W_att2  = (const float*)d_in[17];
    const float* b_att2  = (const float*)d_in[18];

    s16x8* wpk = (s16x8*)d_ws;

    prep_kernel<<<dim3(128), dim3(64), 0, stream>>>(
        W_enc, W_self0, W_self1, W_rel0, W_att0, W_att1, W_rel1, W_rel2, wpk);

    const int nB   = in_sizes[0] / (NN * NCL);   // 8192
    const int grid = nB / NG;                    // 4096

    gh_kernel<<<dim3(grid), dim3(NT), 0, stream>>>(
        S, b_enc, b_self0, b_self1,
        W_rel0, b_rel0, b_rel1, b_rel2,
        W_att0, b_att0, b_att1, W_att2, b_att2,
        wpk, (float*)d_out);
}